// Round 8
// baseline (95.613 us; speedup 1.0000x reference)
//
#include <hip/hip_runtime.h>

#define N_ATOMS 250000
#define NR 8
#define BLK 512          // threads per block
#define NP 36            // tril pairs
#define NBLK ((N_ATOMS + BLK - 1) / BLK)   // 489

typedef float f4 __attribute__((ext_vector_type(4)));

// R7 with ONE change: plain stores instead of __builtin_nontemporal_store
// (isolating the NT store path's write-bandwidth effect; everything else
// byte-identical: wave-private LDS, no barriers, XCD swizzle, 2-burst reads).
__global__ __launch_bounds__(BLK, 4) void moment_contr_kernel(
    const float* __restrict__ m1,   // [A, 8, 3]
    const float* __restrict__ m2,   // [A, 8, 3, 3]
    float* __restrict__ out)        // out[p*2000000 + t*250000 + a]
{
    __shared__ float sbuf[BLK / 64][NP][64];   // 8 x 9 KB = 72 KB

    // --- bijective XCD-chunked swizzle (489 % 8 != 0) ---
    const int orig = blockIdx.x;
    const int q = NBLK / 8, r = NBLK % 8;      // 61, 1
    const int xcd = orig & 7;
    const int wgid = (xcd < r ? xcd * (q + 1)
                              : r * (q + 1) + (xcd - r) * q) + (orig >> 3);

    const int tid  = threadIdx.x;
    const int wid  = tid >> 6;
    const int lane = tid & 63;
    const long long wbase = (long long)wgid * BLK + (long long)wid * 64;
    const long long a = wbase + lane;
    const bool live = (a < N_ATOMS);

    float (*swave)[64] = sbuf[wid];   // this wave's private slice

    // ---- m1[a]: 24 floats, VGPR-resident throughout ----
    float m1v[24];
    if (live) {
        const f4* p = reinterpret_cast<const f4*>(m1 + (size_t)a * 24);
        #pragma unroll
        for (int k = 0; k < 6; ++k) {
            f4 v = p[k];
            m1v[4*k+0] = v.x; m1v[4*k+1] = v.y;
            m1v[4*k+2] = v.z; m1v[4*k+3] = v.w;
        }
    } else {
        #pragma unroll
        for (int k = 0; k < 24; ++k) m1v[k] = 0.f;
    }

    const float* m2a = m2 + (size_t)a * 72;   // 288 B/atom, 16B-aligned

    #pragma unroll
    for (int th = 0; th < 2; ++th) {
        // ---- burst-load half of m2: 36 floats = 9x dwordx4, 144 B/lane ----
        float m2h[36];
        if (live) {
            const f4* ph = reinterpret_cast<const f4*>(m2a + th * 36);
            #pragma unroll
            for (int k = 0; k < 9; ++k) {
                f4 v = ph[k];
                m2h[4*k+0] = v.x; m2h[4*k+1] = v.y;
                m2h[4*k+2] = v.z; m2h[4*k+3] = v.w;
            }
        } else {
            #pragma unroll
            for (int k = 0; k < 36; ++k) m2h[k] = 0.f;
        }

        // ---- 4 t-passes of pure compute + write (no loads) ----
        #pragma unroll
        for (int t4 = 0; t4 < 4; ++t4) {
            const int t = th * 4 + t4;

            // B[s][i] = sum_j m1[s,j] * m2[t,i,j]
            float B[24];
            #pragma unroll
            for (int s = 0; s < NR; ++s) {
                #pragma unroll
                for (int i = 0; i < 3; ++i) {
                    B[s*3+i] = m1v[s*3+0] * m2h[t4*9 + i*3 + 0]
                             + m1v[s*3+1] * m2h[t4*9 + i*3 + 1]
                             + m1v[s*3+2] * m2h[t4*9 + i*3 + 2];
                }
            }

            // contr[r,s,t] -> wave-private LDS; p = r*(r+1)/2 + s (tril order)
            #pragma unroll
            for (int rr = 0; rr < NR; ++rr) {
                #pragma unroll
                for (int s = 0; s <= rr; ++s) {
                    const int p = rr*(rr+1)/2 + s;
                    swave[p][lane] = m1v[rr*3+0] * B[s*3+0]
                                   + m1v[rr*3+1] * B[s*3+1]
                                   + m1v[rr*3+2] * B[s*3+2];
                }
            }

            // wave-internal visibility only (no block barrier)
            asm volatile("s_waitcnt lgkmcnt(0)" ::: "memory");

            // ---- writeout: 36 regions x 64 floats = 9 dwordx4/lane ----
            // p = it*4 + lane/16, sub = (4*lane)%64: each 16-lane group emits
            // one contiguous 256 B segment; b128 LDS read conflict-free.
            #pragma unroll
            for (int it = 0; it < 9; ++it) {
                const int p   = it * 4 + (lane >> 4);
                const int sub = (4 * lane) & 63;
                if (wbase + sub + 4 <= N_ATOMS) {
                    f4 v = *reinterpret_cast<const f4*>(&swave[p][sub]);
                    *reinterpret_cast<f4*>(
                        out + (size_t)p * (NR * N_ATOMS)
                            + (size_t)t * N_ATOMS + wbase + sub) = v;
                }
            }
        }
    }
}

extern "C" void kernel_launch(void* const* d_in, const int* in_sizes, int n_in,
                              void* d_out, int out_size, void* d_ws, size_t ws_size,
                              hipStream_t stream) {
    const float* m1 = (const float*)d_in[0];
    const float* m2 = (const float*)d_in[1];
    float* out = (float*)d_out;

    hipLaunchKernelGGL(moment_contr_kernel, dim3(NBLK), dim3(BLK), 0, stream,
                       m1, m2, out);
}

// Round 9
// 73.961 us; speedup vs baseline: 1.2927x; 1.2927x over previous
//
#include <hip/hip_runtime.h>

#define N_ATOMS 250000
#define NR 8
#define BLK 512          // threads per block
#define NP 36            // tril pairs
#define NBLK ((N_ATOMS + BLK - 1) / BLK)   // 489

typedef float f4 __attribute__((ext_vector_type(4)));

// R7 variant: ALL reads (m1 + full m2 = 384 B/lane, 24x dwordx4) issued in one
// upfront burst; then 8 t-passes of pure compute + NT writeout (zero loads).
// Chip-wide this separates the read stream from the write stream temporally.
// Cost: ~130 VGPR -> 2 waves/SIMD (launch_bounds(512,2)).
__global__ __launch_bounds__(BLK, 2) void moment_contr_kernel(
    const float* __restrict__ m1,   // [A, 8, 3]
    const float* __restrict__ m2,   // [A, 8, 3, 3]
    float* __restrict__ out)        // out[p*2000000 + t*250000 + a]
{
    __shared__ float sbuf[BLK / 64][NP][64];   // 8 x 9 KB = 72 KB

    // --- bijective XCD-chunked swizzle (489 % 8 != 0) ---
    const int orig = blockIdx.x;
    const int q = NBLK / 8, r = NBLK % 8;      // 61, 1
    const int xcd = orig & 7;
    const int wgid = (xcd < r ? xcd * (q + 1)
                              : r * (q + 1) + (xcd - r) * q) + (orig >> 3);

    const int tid  = threadIdx.x;
    const int wid  = tid >> 6;
    const int lane = tid & 63;
    const long long wbase = (long long)wgid * BLK + (long long)wid * 64;
    const long long a = wbase + lane;
    const bool live = (a < N_ATOMS);

    float (*swave)[64] = sbuf[wid];   // this wave's private slice

    // ---- upfront read burst: m1 (6x f4) + full m2 (18x f4) ----
    float m1v[24];
    float m2v[72];
    if (live) {
        const f4* p1 = reinterpret_cast<const f4*>(m1 + (size_t)a * 24);
        const f4* p2 = reinterpret_cast<const f4*>(m2 + (size_t)a * 72);
        #pragma unroll
        for (int k = 0; k < 6; ++k) {
            f4 v = p1[k];
            m1v[4*k+0] = v.x; m1v[4*k+1] = v.y;
            m1v[4*k+2] = v.z; m1v[4*k+3] = v.w;
        }
        #pragma unroll
        for (int k = 0; k < 18; ++k) {
            f4 v = p2[k];
            m2v[4*k+0] = v.x; m2v[4*k+1] = v.y;
            m2v[4*k+2] = v.z; m2v[4*k+3] = v.w;
        }
    } else {
        #pragma unroll
        for (int k = 0; k < 24; ++k) m1v[k] = 0.f;
        #pragma unroll
        for (int k = 0; k < 72; ++k) m2v[k] = 0.f;
    }

    // ---- 8 t-passes of pure compute + NT write (no loads at all) ----
    #pragma unroll
    for (int t = 0; t < NR; ++t) {
        // B[s][i] = sum_j m1[s,j] * m2[t,i,j]
        float B[24];
        #pragma unroll
        for (int s = 0; s < NR; ++s) {
            #pragma unroll
            for (int i = 0; i < 3; ++i) {
                B[s*3+i] = m1v[s*3+0] * m2v[t*9 + i*3 + 0]
                         + m1v[s*3+1] * m2v[t*9 + i*3 + 1]
                         + m1v[s*3+2] * m2v[t*9 + i*3 + 2];
            }
        }

        // contr[r,s,t] -> wave-private LDS; p = r*(r+1)/2 + s (tril order)
        #pragma unroll
        for (int rr = 0; rr < NR; ++rr) {
            #pragma unroll
            for (int s = 0; s <= rr; ++s) {
                const int p = rr*(rr+1)/2 + s;
                swave[p][lane] = m1v[rr*3+0] * B[s*3+0]
                               + m1v[rr*3+1] * B[s*3+1]
                               + m1v[rr*3+2] * B[s*3+2];
            }
        }

        // wave-internal visibility only (no block barrier)
        asm volatile("s_waitcnt lgkmcnt(0)" ::: "memory");

        // ---- writeout: 36 regions x 64 floats = 9 NT dwordx4/lane ----
        // p = it*4 + lane/16, sub = (4*lane)%64: each 16-lane group emits one
        // contiguous 256 B segment; b128 LDS read conflict-free.
        #pragma unroll
        for (int it = 0; it < 9; ++it) {
            const int p   = it * 4 + (lane >> 4);
            const int sub = (4 * lane) & 63;
            if (wbase + sub + 4 <= N_ATOMS) {
                f4 v = *reinterpret_cast<const f4*>(&swave[p][sub]);
                __builtin_nontemporal_store(
                    v, reinterpret_cast<f4*>(
                        out + (size_t)p * (NR * N_ATOMS)
                            + (size_t)t * N_ATOMS + wbase + sub));
            }
        }
    }
}

extern "C" void kernel_launch(void* const* d_in, const int* in_sizes, int n_in,
                              void* d_out, int out_size, void* d_ws, size_t ws_size,
                              hipStream_t stream) {
    const float* m1 = (const float*)d_in[0];
    const float* m2 = (const float*)d_in[1];
    float* out = (float*)d_out;

    hipLaunchKernelGGL(moment_contr_kernel, dim3(NBLK), dim3(BLK), 0, stream,
                       m1, m2, out);
}

// Round 10
// 68.128 us; speedup vs baseline: 1.4034x; 1.0856x over previous
//
#include <hip/hip_runtime.h>

#define N_ATOMS 250000
#define NR 8
#define BLK 256          // threads per block == atoms per block
#define NP 36            // tril pairs
#define NBLK ((N_ATOMS + BLK - 1) / BLK)   // 977
 
typedef float f4 __attribute__((ext_vector_type(4)));

// R9 (upfront burst read, NT stores, XCD swizzle) + block-cooperative
// writeout: double-buffered LDS [2][36][256], raw lgkmcnt+s_barrier (no vmcnt
// drain), each (p,t) region written by ONE wave as ONE 1KB dwordx4 burst,
// 9 consecutive regions per wave.
__global__ __launch_bounds__(BLK, 2) void moment_contr_kernel(
    const float* __restrict__ m1,   // [A, 8, 3]
    const float* __restrict__ m2,   // [A, 8, 3, 3]
    float* __restrict__ out)        // out[p*2000000 + t*250000 + a]
{
    __shared__ float sbuf[2][NP][BLK];   // 2 x 36 KB = 72 KB -> 2 blocks/CU

    // --- bijective XCD-chunked swizzle (977 % 8 != 0) ---
    const int orig = blockIdx.x;
    const int q = NBLK / 8, r = NBLK % 8;      // 122, 1
    const int xcd = orig & 7;
    const int wgid = (xcd < r ? xcd * (q + 1)
                              : r * (q + 1) + (xcd - r) * q) + (orig >> 3);

    const int tid  = threadIdx.x;
    const int wid  = tid >> 6;      // 0..3
    const int lane = tid & 63;
    const long long block_base = (long long)wgid * BLK;
    const long long a = block_base + tid;
    const bool live = (a < N_ATOMS);

    // ---- upfront read burst: m1 (6x f4) + full m2 (18x f4) ----
    float m1v[24];
    float m2v[72];
    if (live) {
        const f4* p1 = reinterpret_cast<const f4*>(m1 + (size_t)a * 24);
        const f4* p2 = reinterpret_cast<const f4*>(m2 + (size_t)a * 72);
        #pragma unroll
        for (int k = 0; k < 6; ++k) {
            f4 v = p1[k];
            m1v[4*k+0] = v.x; m1v[4*k+1] = v.y;
            m1v[4*k+2] = v.z; m1v[4*k+3] = v.w;
        }
        #pragma unroll
        for (int k = 0; k < 18; ++k) {
            f4 v = p2[k];
            m2v[4*k+0] = v.x; m2v[4*k+1] = v.y;
            m2v[4*k+2] = v.z; m2v[4*k+3] = v.w;
        }
    } else {
        #pragma unroll
        for (int k = 0; k < 24; ++k) m1v[k] = 0.f;
        #pragma unroll
        for (int k = 0; k < 72; ++k) m2v[k] = 0.f;
    }

    // ---- 8 t-passes: compute -> stage buf[t&1] -> raw barrier -> 1KB-run
    //      cooperative NT writeout. Double buffer => 1 barrier per pass.
    //      (Read-completion of buf[i] at pass t is covered by the pass-t+1
    //      lgkmcnt(0) before barrier t+1, which precedes pass-t+2 writes.)
    #pragma unroll
    for (int t = 0; t < NR; ++t) {
        // B[s][i] = sum_j m1[s,j] * m2[t,i,j]
        float B[24];
        #pragma unroll
        for (int s = 0; s < NR; ++s) {
            #pragma unroll
            for (int i = 0; i < 3; ++i) {
                B[s*3+i] = m1v[s*3+0] * m2v[t*9 + i*3 + 0]
                         + m1v[s*3+1] * m2v[t*9 + i*3 + 1]
                         + m1v[s*3+2] * m2v[t*9 + i*3 + 2];
            }
        }

        // contr[r,s,t] -> block LDS buf[t&1]; p = r*(r+1)/2 + s (tril order).
        // stride-1 dword writes per wave: conflict-free.
        #pragma unroll
        for (int rr = 0; rr < NR; ++rr) {
            #pragma unroll
            for (int s = 0; s <= rr; ++s) {
                const int p = rr*(rr+1)/2 + s;
                sbuf[t & 1][p][tid] = m1v[rr*3+0] * B[s*3+0]
                                    + m1v[rr*3+1] * B[s*3+1]
                                    + m1v[rr*3+2] * B[s*3+2];
            }
        }

        // own LDS writes complete, then rendezvous — NO vmcnt drain, so the
        // previous pass's NT stores stay in flight across the barrier.
        asm volatile("s_waitcnt lgkmcnt(0)\n\ts_barrier" ::: "memory");

        // ---- cooperative writeout: wave wid owns p = 9*wid .. 9*wid+8.
        // One ds_read_b128 + one NT dwordx4 per region: 64 lanes x 16 B =
        // 1 KB contiguous per instruction, single-owner per (p,t) region.
        // b128 lane stride 16 B: canonical conflict-free LDS read.
        #pragma unroll
        for (int k = 0; k < 9; ++k) {
            const int p = wid * 9 + k;
            const long long g = block_base + 4 * lane;
            if (g + 4 <= N_ATOMS) {   // N%4==0: exact f4 guard
                f4 v = *reinterpret_cast<const f4*>(&sbuf[t & 1][p][4 * lane]);
                __builtin_nontemporal_store(
                    v, reinterpret_cast<f4*>(
                        out + (size_t)p * (NR * N_ATOMS)
                            + (size_t)t * N_ATOMS + g));
            }
        }
    }
}

extern "C" void kernel_launch(void* const* d_in, const int* in_sizes, int n_in,
                              void* d_out, int out_size, void* d_ws, size_t ws_size,
                              hipStream_t stream) {
    const float* m1 = (const float*)d_in[0];
    const float* m2 = (const float*)d_in[1];
    float* out = (float*)d_out;

    hipLaunchKernelGGL(moment_contr_kernel, dim3(NBLK), dim3(BLK), 0, stream,
                       m1, m2, out);
}